// Round 7
// baseline (392.755 us; speedup 1.0000x reference)
//
#include <hip/hip_runtime.h>

typedef __bf16 bf16x8_t __attribute__((ext_vector_type(8)));
typedef float f32x4_t __attribute__((ext_vector_type(4)));

#define AS1 __attribute__((address_space(1)))
#define AS3 __attribute__((address_space(3)))

__device__ __forceinline__ unsigned short f2b(float f) {
    unsigned u = __builtin_bit_cast(unsigned, f);
    u += 0x7fffu + ((u >> 16) & 1u);
    return (unsigned short)(u >> 16);
}

// ---------------------------------------------------------------------------
// fp32 -> bf16 convert, 4 elems/thread
// ---------------------------------------------------------------------------
__global__ __launch_bounds__(256) void k_f2b(const float* __restrict__ in,
                                             unsigned short* __restrict__ out,
                                             int n4) {
    int i = blockIdx.x * 256 + threadIdx.x;
    if (i >= n4) return;
    float4 v = reinterpret_cast<const float4*>(in)[i];
    ushort4 o;
    o.x = f2b(v.x); o.y = f2b(v.y); o.z = f2b(v.z); o.w = f2b(v.w);
    reinterpret_cast<ushort4*>(out)[i] = o;
}

// ---------------------------------------------------------------------------
// m201-style 8-phase NT-GEMM. C-tile 256x256, BK=64, 512 threads = 8 waves.
// Iteration = 2 K-tiles (t0->dbuf D0, t1->D1), 8 phases; each phase:
//   {ds_read frag subtile; stage 1 half-tile (2 gload_lds); [vmcnt@g3/g7];
//    s_barrier; lgkmcnt(0); sched_barrier(0); setprio(1); 16 MFMA; setprio(0);
//    s_barrier}
// Quadrant order per K-tile: (0,0),(0,1),(1,1),(1,0); reads: g0:A0+B0(12),
// g1:B1(4), g2:A1(8), g3:none (B0 frags cached since g0).
// Stage order (1 half/phase, slot freed >=1 barrier-pair earlier):
//   g0: D1.A1<-t1 | g1..g4: D0.{A0,B0,B1,A1}<-t0+2 | g5..g7: D1.{A0,B0,B1}<-t1+2
// vmcnt(6) before g3's barrier (guards all of t1: 3 halves = 6 loads allowed
// outstanding) and before g7's barrier (guards t0+2). Never 0 mid-loop.
// Prologue: t0 all 4 halves + t1's A0,B0,B1 (14 loads), vmcnt(6), barrier.
// Last iteration: stages g1..g7 suppressed, waits become vmcnt(0).
// Swizzle byte^=((row&7)<<4) on 128B rows, both sides (verified 0 conflicts).
// ---------------------------------------------------------------------------
#define SA(d, h, kof) do {                                                     \
    char* wb_ = smem + (d) * 65536 + (h) * 16384 + wave * 2048;                \
    __builtin_amdgcn_global_load_lds(                                          \
        (const AS1 void*)(pA + (kof) + (size_t)((h) * 128) * lda),             \
        (AS3 void*)wb_, 16, 0, 0);                                             \
    __builtin_amdgcn_global_load_lds(                                          \
        (const AS1 void*)(pA + (kof) + (size_t)((h) * 128 + 8) * lda),         \
        (AS3 void*)(wb_ + 1024), 16, 0, 0);                                    \
} while (0)
#define SB(d, h, kof) do {                                                     \
    char* wb_ = smem + (d) * 65536 + 32768 + (h) * 16384 + wave * 2048;        \
    __builtin_amdgcn_global_load_lds(                                          \
        (const AS1 void*)(pB + (kof) + (size_t)((h) * 128) * ldb),             \
        (AS3 void*)wb_, 16, 0, 0);                                             \
    __builtin_amdgcn_global_load_lds(                                          \
        (const AS1 void*)(pB + (kof) + (size_t)((h) * 128 + 8) * ldb),         \
        (AS3 void*)(wb_ + 1024), 16, 0, 0);                                    \
} while (0)

#define RD_A(d, qm, dst)                                                       \
    _Pragma("unroll") for (int mi = 0; mi < 4; ++mi)                           \
    _Pragma("unroll") for (int ks = 0; ks < 2; ++ks)                           \
        dst[mi][ks] = *reinterpret_cast<const bf16x8_t*>(                      \
            smem + (d) * 65536 + offA[qm][mi][ks]);
#define RD_B(d, qn, dst)                                                       \
    _Pragma("unroll") for (int ni = 0; ni < 2; ++ni)                           \
    _Pragma("unroll") for (int ks = 0; ks < 2; ++ks)                           \
        dst[ni][ks] = *reinterpret_cast<const bf16x8_t*>(                      \
            smem + (d) * 65536 + offB[qn][ni][ks]);

#define MFMA_Q(qm, qn, A_, B_)                                                 \
    __builtin_amdgcn_s_setprio(1);                                             \
    _Pragma("unroll") for (int mi = 0; mi < 4; ++mi)                           \
    _Pragma("unroll") for (int ni = 0; ni < 2; ++ni) {                         \
        acc[qm][qn][mi][ni] = __builtin_amdgcn_mfma_f32_16x16x32_bf16(         \
            A_[mi][0], B_[ni][0], acc[qm][qn][mi][ni], 0, 0, 0);               \
        acc[qm][qn][mi][ni] = __builtin_amdgcn_mfma_f32_16x16x32_bf16(         \
            A_[mi][1], B_[ni][1], acc[qm][qn][mi][ni], 0, 0, 0);               \
    }                                                                          \
    __builtin_amdgcn_s_setprio(0)

#define PH_SYNC()                                                              \
    asm volatile("s_barrier" ::: "memory");                                    \
    asm volatile("s_waitcnt lgkmcnt(0)" ::: "memory");                         \
    __builtin_amdgcn_sched_barrier(0)
#define PH_END() asm volatile("s_barrier" ::: "memory")

#define ITER(L, kt1, kt2, kt3) do {                                            \
    bf16x8_t a_[4][2], b0_[2][2], b1_[2][2];                                   \
    /* g0: t0 quad(0,0) */                                                     \
    RD_A(0, 0, a_); RD_B(0, 0, b0_); SA(1, 1, (kt1));                          \
    PH_SYNC(); MFMA_Q(0, 0, a_, b0_); PH_END();                                \
    /* g1: quad(0,1) */                                                        \
    RD_B(0, 1, b1_); if (!(L)) SA(0, 0, (kt2));                                \
    PH_SYNC(); MFMA_Q(0, 1, a_, b1_); PH_END();                                \
    /* g2: quad(1,1) */                                                        \
    RD_A(0, 1, a_); if (!(L)) SB(0, 0, (kt2));                                 \
    PH_SYNC(); MFMA_Q(1, 1, a_, b1_); PH_END();                                \
    /* g3: quad(1,0) */                                                        \
    if (!(L)) { SB(0, 1, (kt2));                                               \
                asm volatile("s_waitcnt vmcnt(6)" ::: "memory"); }             \
    else      { asm volatile("s_waitcnt vmcnt(0)" ::: "memory"); }             \
    PH_SYNC(); MFMA_Q(1, 0, a_, b0_); PH_END();                                \
    /* g4: t1 quad(0,0) */                                                     \
    RD_A(1, 0, a_); RD_B(1, 0, b0_); if (!(L)) SA(0, 1, (kt2));                \
    PH_SYNC(); MFMA_Q(0, 0, a_, b0_); PH_END();                                \
    /* g5: quad(0,1) */                                                        \
    RD_B(1, 1, b1_); if (!(L)) SA(1, 0, (kt3));                                \
    PH_SYNC(); MFMA_Q(0, 1, a_, b1_); PH_END();                                \
    /* g6: quad(1,1) */                                                        \
    RD_A(1, 1, a_); if (!(L)) SB(1, 0, (kt3));                                 \
    PH_SYNC(); MFMA_Q(1, 1, a_, b1_); PH_END();                                \
    /* g7: quad(1,0) */                                                        \
    if (!(L)) { SB(1, 1, (kt3));                                               \
                asm volatile("s_waitcnt vmcnt(6)" ::: "memory"); }             \
    else      { asm volatile("s_waitcnt vmcnt(0)" ::: "memory"); }             \
    PH_SYNC(); MFMA_Q(1, 0, a_, b0_); PH_END();                                \
} while (0)

__device__ __forceinline__ void gemm_mainloop(
    const unsigned short* __restrict__ A, int lda,
    const unsigned short* __restrict__ B, int ldb,
    int K, char* smem, f32x4_t acc[2][2][4][2]) {
    const int tid = threadIdx.x;
    const int wave = tid >> 6, lane = tid & 63;
    const int wsm = (wave >> 2) & 1, wsn = wave & 3;
    const int fr = lane & 15, g = lane >> 4;
    const int srow8 = lane >> 3;
    const int scolB = ((lane & 7) * 16) ^ (srow8 << 4);  // pre-swizzled byte

    const unsigned short* pA = A + (size_t)(wave * 16 + srow8) * lda + (scolB >> 1);
    const unsigned short* pB = B + (size_t)(wave * 16 + srow8) * ldb + (scolB >> 1);

    int offA[2][4][2], offB[2][2][2];
#pragma unroll
    for (int qm = 0; qm < 2; ++qm)
#pragma unroll
        for (int mi = 0; mi < 4; ++mi)
#pragma unroll
            for (int ks = 0; ks < 2; ++ks)
                offA[qm][mi][ks] = qm * 16384 + (wsm * 64 + mi * 16 + fr) * 128 +
                                   ((ks * 64 + g * 16) ^ ((fr & 7) << 4));
#pragma unroll
    for (int qn = 0; qn < 2; ++qn)
#pragma unroll
        for (int ni = 0; ni < 2; ++ni)
#pragma unroll
            for (int ks = 0; ks < 2; ++ks)
                offB[qn][ni][ks] = 32768 + qn * 16384 + (wsn * 32 + ni * 16 + fr) * 128 +
                                   ((ks * 64 + g * 16) ^ ((fr & 7) << 4));

#pragma unroll
    for (int qm = 0; qm < 2; ++qm)
#pragma unroll
        for (int qn = 0; qn < 2; ++qn)
#pragma unroll
            for (int mi = 0; mi < 4; ++mi)
#pragma unroll
                for (int ni = 0; ni < 2; ++ni)
                    acc[qm][qn][mi][ni] = (f32x4_t){0.f, 0.f, 0.f, 0.f};

    const int NT = K >> 6;        // even
    const int NI = NT >> 1;

    // prologue: tile0 all 4 halves + tile1's A0,B0,B1  (14 loads)
    SA(0, 0, 0); SB(0, 0, 0); SB(0, 1, 0); SA(0, 1, 0);
    SA(1, 0, 64); SB(1, 0, 64); SB(1, 1, 64);
    asm volatile("s_waitcnt vmcnt(6)" ::: "memory");   // tile0 landed
    asm volatile("s_barrier" ::: "memory");

    size_t kk = 0;
    for (int i = 0; i < NI - 1; ++i, kk += 128)
        ITER(0, kk + 64, kk + 128, kk + 192);
    ITER(1, kk + 64, kk + 128, kk + 192);
}

// Epilogue: acc[qm][qn][mi][ni][j] ->
//   row = tm + qm*128 + wsm*64 + mi*16 + (lane>>4)*4 + j
//   col = tn + qn*128 + wsn*32 + ni*16 + (lane&15)
#define EPILOGUE_IDX                                            \
    const int lane = threadIdx.x & 63, wave = threadIdx.x >> 6; \
    const int e_r0 = ((wave >> 2) & 1) * 64 + (lane >> 4) * 4;  \
    const int e_c0 = (wave & 3) * 32 + (lane & 15);

#define EPILOGUE_LOOP(...)                                      \
    _Pragma("unroll") for (int qm = 0; qm < 2; ++qm)            \
    _Pragma("unroll") for (int qn = 0; qn < 2; ++qn)            \
    _Pragma("unroll") for (int mi = 0; mi < 4; ++mi)            \
    _Pragma("unroll") for (int ni = 0; ni < 2; ++ni)            \
    _Pragma("unroll") for (int j = 0; j < 4; ++j) { __VA_ARGS__ }

// Interleaved q/k layout: per batch z (8 total), base elem z*4194304:
//   q_z[2048][1024] at +0, k_z[2048][1024] at +2097152.
// Softmax output P_z[2048][2048] bf16 later overlays exactly this region.

// ---------------------------------------------------------------------------
// QKV GEMM, Q/K half: M=16384 tokens, N=2048 (w_qkv rows 0..2047), K=1024
// ---------------------------------------------------------------------------
__global__ __launch_bounds__(512, 2) void k_gemm_qkv_qk(
    const unsigned short* __restrict__ x, const unsigned short* __restrict__ w,
    unsigned short* __restrict__ qk) {
    __shared__ __align__(16) char smem[131072];
    const size_t tm = (size_t)blockIdx.x * 256, tn = (size_t)blockIdx.y * 256;
    f32x4_t acc[2][2][4][2];
    gemm_mainloop(x + tm * 1024, 1024, w + tn * 1024, 1024, 1024, smem, acc);
    EPILOGUE_IDX
    EPILOGUE_LOOP(
        size_t m = tm + qm * 128 + e_r0 + mi * 16 + j;
        size_t z = m >> 11;
        size_t nloc = m & 2047;
        int n = (int)tn + qn * 128 + e_c0 + ni * 16;
        unsigned short v = f2b(acc[qm][qn][mi][ni][j]);
        size_t base = z * 4194304 + nloc * 1024;
        if (n < 1024) qk[base + n] = v;
        else          qk[base + 2097152 + (n - 1024)] = v;
    )
}

// ---------------------------------------------------------------------------
// QKV GEMM, V^T half (operands swapped): M=1024 (v-weight rows), N=16384
// tokens, K=1024.  vt[c][token] = v[token][c], coalesced stores.
// ---------------------------------------------------------------------------
__global__ __launch_bounds__(512, 2) void k_gemm_vt(
    const unsigned short* __restrict__ wv, const unsigned short* __restrict__ x,
    unsigned short* __restrict__ vt) {
    __shared__ __align__(16) char smem[131072];
    const size_t tm = (size_t)blockIdx.x * 256, tn = (size_t)blockIdx.y * 256;
    f32x4_t acc[2][2][4][2];
    gemm_mainloop(wv + tm * 1024, 1024, x + tn * 1024, 1024, 1024, smem, acc);
    EPILOGUE_IDX
    EPILOGUE_LOOP(
        size_t m = tm + qm * 128 + e_r0 + mi * 16 + j;   // c
        size_t n = tn + qn * 128 + e_c0 + ni * 16;       // token
        vt[m * 16384 + n] = f2b(acc[qm][qn][mi][ni][j]);
    )
}

// ---------------------------------------------------------------------------
// Scores: batch z = z0 + blockIdx.z; S[zlocal][nq][mk] = (q·k) * 1/32, fp32
// ---------------------------------------------------------------------------
__global__ __launch_bounds__(512, 2) void k_gemm_scores(
    const unsigned short* __restrict__ qk, float* __restrict__ S, int z0) {
    __shared__ __align__(16) char smem[131072];
    const size_t z = z0 + blockIdx.z;
    const size_t tm = (size_t)blockIdx.x * 256, tn = (size_t)blockIdx.y * 256;
    const unsigned short* qz = qk + z * 4194304;
    const unsigned short* kz = qz + 2097152;
    f32x4_t acc[2][2][4][2];
    gemm_mainloop(qz + tm * 1024, 1024, kz + tn * 1024, 1024, 1024, smem, acc);
    EPILOGUE_IDX
    float* Sz = S + (size_t)blockIdx.z * 4194304;
    EPILOGUE_LOOP(
        size_t m = tm + qm * 128 + e_r0 + mi * 16 + j;
        size_t n = tn + qn * 128 + e_c0 + ni * 16;
        Sz[m * 2048 + n] = acc[qm][qn][mi][ni][j] * 0.03125f;
    )
}

// ---------------------------------------------------------------------------
// Row softmax: NZ*2048 rows x 2048, fp32 in -> bf16 out (P overlays q/k)
// ---------------------------------------------------------------------------
__global__ __launch_bounds__(256) void k_softmax(const float* __restrict__ S,
                                                 unsigned short* __restrict__ qk,
                                                 int z0) {
    const size_t r = blockIdx.x;                 // row within chunk
    const int t = threadIdx.x, wv = t >> 6, ln = t & 63;
    const float4* s4 = reinterpret_cast<const float4*>(S + r * 2048);
    float4 a = s4[t], b = s4[t + 256];
    float vals[8] = {a.x, a.y, a.z, a.w, b.x, b.y, b.z, b.w};

    float mx = vals[0];
#pragma unroll
    for (int i = 1; i < 8; ++i) mx = fmaxf(mx, vals[i]);
#pragma unroll
    for (int i = 32; i > 0; i >>= 1) mx = fmaxf(mx, __shfl_xor(mx, i, 64));
    __shared__ float red[8];
    if (ln == 0) red[wv] = mx;
    __syncthreads();
    mx = fmaxf(fmaxf(red[0], red[1]), fmaxf(red[2], red[3]));

    float ex[8], s = 0.f;
#pragma unroll
    for (int i = 0; i < 8; ++i) { ex[i] = __expf(vals[i] - mx); s += ex[i]; }
#pragma unroll
    for (int i = 32; i > 0; i >>= 1) s += __shfl_xor(s, i, 64);
    if (ln == 0) red[4 + wv] = s;
    __syncthreads();
    s = (red[4] + red[5]) + (red[6] + red[7]);
    float inv = 1.0f / s;

    ushort4 pa, pb;
    pa.x = f2b(ex[0] * inv); pa.y = f2b(ex[1] * inv);
    pa.z = f2b(ex[2] * inv); pa.w = f2b(ex[3] * inv);
    pb.x = f2b(ex[4] * inv); pb.y = f2b(ex[5] * inv);
    pb.z = f2b(ex[6] * inv); pb.w = f2b(ex[7] * inv);

    const size_t zg = z0 + (r >> 11), nloc = r & 2047;
    ushort4* p4 = reinterpret_cast<ushort4*>(qk + zg * 4194304 + nloc * 2048);
    p4[t] = pa;
    p4[t + 256] = pb;
}

// ---------------------------------------------------------------------------
// PV as O^T: batch z = z0+blockIdx.z, O^T[c][n] = sum_m vt[c][m] * P[n][m]
// M=1024 (c), N=2048 (n), K=2048.  Stores apply the swapaxes-reshape
// scramble o2[2c + (n>>10)][n&1023] = o[n][c] -> coalesced in n.
// ---------------------------------------------------------------------------
__global__ __launch_bounds__(512, 2) void k_gemm_pv(
    const unsigned short* __restrict__ vt, const unsigned short* __restrict__ qk,
    unsigned short* __restrict__ ob, int z0) {
    __shared__ __align__(16) char smem[131072];
    const size_t z = z0 + blockIdx.z;
    const size_t tm = (size_t)blockIdx.x * 256, tn = (size_t)blockIdx.y * 256;
    const unsigned short* P = qk + z * 4194304;
    f32x4_t acc[2][2][4][2];
    gemm_mainloop(vt + tm * 16384 + z * 2048, 16384,
                  P + tn * 2048, 2048, 2048, smem, acc);
    EPILOGUE_IDX
    unsigned short* oz = ob + z * 2097152;
    EPILOGUE_LOOP(
        size_t m = tm + qm * 128 + e_r0 + mi * 16 + j;   // c
        size_t n = tn + qn * 128 + e_c0 + ni * 16;       // token n within batch
        oz[(2 * m + (n >> 10)) * 1024 + (n & 1023)] = f2b(acc[qm][qn][mi][ni][j]);
    )
}

// ---------------------------------------------------------------------------
// Proj: out[m][d] = sum_j o2[m][j] * w_proj[d][j] + b_proj[d], fp32 out
// M=16384, N=1024, K=1024
// ---------------------------------------------------------------------------
__global__ __launch_bounds__(512, 2) void k_gemm_proj(
    const unsigned short* __restrict__ o2, const unsigned short* __restrict__ w,
    const float* __restrict__ bias, float* __restrict__ out) {
    __shared__ __align__(16) char smem[131072];
    const size_t tm = (size_t)blockIdx.x * 256, tn = (size_t)blockIdx.y * 256;
    f32x4_t acc[2][2][4][2];
    gemm_mainloop(o2 + tm * 1024, 1024, w + tn * 1024, 1024, 1024, smem, acc);
    EPILOGUE_IDX
    EPILOGUE_LOOP(
        size_t m = tm + qm * 128 + e_r0 + mi * 16 + j;
        size_t n = tn + qn * 128 + e_c0 + ni * 16;
        out[m * 1024 + n] = acc[qm][qn][mi][ni][j] + bias[n];
    )
}

// ---------------------------------------------------------------------------
extern "C" void kernel_launch(void* const* d_in, const int* in_sizes, int n_in,
                              void* d_out, int out_size, void* d_ws, size_t ws_size,
                              hipStream_t stream) {
    const float* x     = (const float*)d_in[0];
    const float* wqkv  = (const float*)d_in[1];
    const float* wproj = (const float*)d_in[2];
    const float* bproj = (const float*)d_in[3];
    float* out = (float*)d_out;
    char* ws = (char*)d_ws;

    // workspace layout (bytes):
    const size_t off_xb    = 0;             // 33,554,432 x bf16 (obuf overlays)
    const size_t off_wqkv  = 33554432;      //  6,291,456
    const size_t off_wproj = 39845888;      //  2,097,152
    const size_t off_qk    = 41943040;      // 67,108,864 interleaved q/k (P overlays)
    const size_t off_vt    = 109051904;     // 33,554,432
    const size_t off_S     = 142606336;     // NZ * 16,777,216 fp32 logits chunk
    // adaptive chunk: largest NZ in {8,4,2,1} that fits
    int NZ = 0;
    for (int c = 8; c >= 1; c >>= 1)
        if (off_S + (size_t)c * 16777216 <= ws_size) { NZ = c; break; }
    if (NZ == 0) return;  // fail loudly via absmax check

    unsigned short* xb     = (unsigned short*)(ws + off_xb);
    unsigned short* wqkvb  = (unsigned short*)(ws + off_wqkv);
    unsigned short* wprojb = (unsigned short*)(ws + off_wproj);
    unsigned short* qkb    = (unsigned short*)(ws + off_qk);
    unsigned short* vtb    = (unsigned short*)(ws + off_vt);
    float*          Sf     = (float*)(ws + off_S);
    unsigned short* obuf   = (unsigned short*)(ws + off_xb);  // overlay

    k_f2b<<<16384, 256, 0, stream>>>(x, xb, 4194304);
    k_f2b<<<3072, 256, 0, stream>>>(wqkv, wqkvb, 786432);
    k_f2b<<<1024, 256, 0, stream>>>(wproj, wprojb, 262144);

    k_gemm_qkv_qk<<<dim3(64, 8), 512, 0, stream>>>(xb, wqkvb, qkb);
    k_gemm_vt<<<dim3(4, 64), 512, 0, stream>>>(wqkvb + (size_t)2048 * 1024, xb, vtb);

    for (int z0 = 0; z0 < 8; z0 += NZ) {
        k_gemm_scores<<<dim3(8, 8, NZ), 512, 0, stream>>>(qkb, Sf, z0);
        k_softmax<<<NZ * 2048, 256, 0, stream>>>(Sf, qkb, z0);
        k_gemm_pv<<<dim3(4, 8, NZ), 512, 0, stream>>>(vtb, qkb, obuf, z0);
    }
    k_gemm_proj<<<dim3(64, 4), 512, 0, stream>>>(obuf, wprojb, bproj, out);
}

// Round 8
// 328.829 us; speedup vs baseline: 1.1944x; 1.1944x over previous
//
#include <hip/hip_runtime.h>

typedef __bf16 bf16x8_t __attribute__((ext_vector_type(8)));
typedef float f32x4_t __attribute__((ext_vector_type(4)));

#define AS1 __attribute__((address_space(1)))
#define AS3 __attribute__((address_space(3)))

__device__ __forceinline__ unsigned short f2b(float f) {
    unsigned u = __builtin_bit_cast(unsigned, f);
    u += 0x7fffu + ((u >> 16) & 1u);
    return (unsigned short)(u >> 16);
}
__device__ __forceinline__ float b2f(unsigned short s) {
    return __builtin_bit_cast(float, (unsigned)s << 16);
}

// ---------------------------------------------------------------------------
// fp32 -> bf16 convert, 4 elems/thread
// ---------------------------------------------------------------------------
__global__ __launch_bounds__(256) void k_f2b(const float* __restrict__ in,
                                             unsigned short* __restrict__ out,
                                             int n4) {
    int i = blockIdx.x * 256 + threadIdx.x;
    if (i >= n4) return;
    float4 v = reinterpret_cast<const float4*>(in)[i];
    ushort4 o;
    o.x = f2b(v.x); o.y = f2b(v.y); o.z = f2b(v.z); o.w = f2b(v.w);
    reinterpret_cast<ushort4*>(out)[i] = o;
}

// ---------------------------------------------------------------------------
// 2-phase quadrant NT-GEMM. C-tile 256x256, BK=64, 512 threads = 8 waves.
// Per K-tile, 2 phases x 32 MFMA (quadrants (0,0)+(0,1), then (1,1)+(1,0));
// within a quadrant the 8 waves are 2M x 4N, wave = 64x32 = 4x2 frags of
// 16x16x32 bf16 MFMA. LDS: 2 buffers x {A: 2x16KB, B: 2x16KB} = 128KB.
// Staging 1 K-tile ahead into buf^1: PhA stages {A0,B0}(t+1) (4 loads),
// PhB stages {B1,A1}(t+1) (4 loads). Steady-state queue before PhA =
// [A0B0(t):4][B1A1(t):4] -> vmcnt(2) drains A0,B0,B1 (leaves A1);
// before PhB 6 outstanding -> vmcnt(4) drains A1. Waits are BEFORE their
// barrier (cross-wave landing); stage buffer != read buffer within an iter;
// overwritten slots' last readers are >=2 barriers earlier. Tail: 2 / 0.
// Prologue stage order A0,B0,B1,A1 == steady-state queue order.
// Swizzle byte^=((row&7)<<4) on 128B rows, both sides (0 conflicts, verified).
// Vs round 6: barriers per K-tile 4 -> 2 (m233: barrier+drain overhead is the
// dominant stall in lockstep 1-block/CU schedules; amortize over 2x MFMA).
// ---------------------------------------------------------------------------
#define STA(h, i)                                                              \
    __builtin_amdgcn_global_load_lds(                                         \
        (const AS1 void*)(pA + kof + (size_t)((h) * 128 + (i) * 8) * lda),    \
        (AS3 void*)(wb + (h) * 16384 + wave * 2048 + (i) * 1024), 16, 0, 0)
#define STB(h, i)                                                              \
    __builtin_amdgcn_global_load_lds(                                         \
        (const AS1 void*)(pB + kof + (size_t)((h) * 128 + (i) * 8) * ldb),    \
        (AS3 void*)(wb + 32768 + (h) * 16384 + wave * 2048 + (i) * 1024), 16, 0, 0)

#define READ_A(qm)                                                             \
    _Pragma("unroll") for (int mi = 0; mi < 4; ++mi)                           \
        _Pragma("unroll") for (int ks = 0; ks < 2; ++ks)                       \
            af[mi][ks] = *reinterpret_cast<const bf16x8_t*>(rb + offA[qm][mi][ks]);
#define READ_B(qn)                                                             \
    _Pragma("unroll") for (int ni = 0; ni < 2; ++ni)                           \
        _Pragma("unroll") for (int ks = 0; ks < 2; ++ks)                       \
            bf[qn][ni][ks] = *reinterpret_cast<const bf16x8_t*>(rb + offB[qn][ni][ks]);

#define MFMA_QUAD(qm, qn)                                                      \
    __builtin_amdgcn_s_setprio(1);                                             \
    _Pragma("unroll") for (int mi = 0; mi < 4; ++mi)                           \
        _Pragma("unroll") for (int ni = 0; ni < 2; ++ni) {                     \
            acc[qm][qn][mi][ni] = __builtin_amdgcn_mfma_f32_16x16x32_bf16(     \
                af[mi][0], bf[qn][ni][0], acc[qm][qn][mi][ni], 0, 0, 0);       \
            acc[qm][qn][mi][ni] = __builtin_amdgcn_mfma_f32_16x16x32_bf16(     \
                af[mi][1], bf[qn][ni][1], acc[qm][qn][mi][ni], 0, 0, 0);       \
        }                                                                      \
    __builtin_amdgcn_s_setprio(0);

template <bool LAST>
__device__ __forceinline__ void tile_step(
    const char* rb, char* wb, size_t kof,
    const unsigned short* pA, const unsigned short* pB, int lda, int ldb,
    int wave, const int offA[2][4][2], const int offB[2][2][2],
    f32x4_t acc[2][2][4][2]) {
    bf16x8_t af[4][2], bf[2][2][2];
    // ---- PhA: quadrants (0,0),(0,1); needs A0,B0,B1 of tile t
    asm volatile("s_waitcnt vmcnt(2)" ::: "memory");   // leaves A1(t) in flight
    asm volatile("s_barrier" ::: "memory");
    if constexpr (!LAST) { STA(0, 0); STA(0, 1); STB(0, 0); STB(0, 1); }
    READ_A(0); READ_B(0); READ_B(1);
    MFMA_QUAD(0, 0);
    MFMA_QUAD(0, 1);
    // ---- PhB: quadrants (1,1),(1,0); needs A1 of tile t
    if constexpr (LAST) asm volatile("s_waitcnt vmcnt(0)" ::: "memory");
    else                asm volatile("s_waitcnt vmcnt(4)" ::: "memory");
    asm volatile("s_barrier" ::: "memory");
    if constexpr (!LAST) { STB(1, 0); STB(1, 1); STA(1, 0); STA(1, 1); }
    READ_A(1);
    MFMA_QUAD(1, 1);
    MFMA_QUAD(1, 0);
}

__device__ __forceinline__ void gemm_mainloop(
    const unsigned short* __restrict__ A, int lda,
    const unsigned short* __restrict__ B, int ldb,
    int K, char* smem, f32x4_t acc[2][2][4][2]) {
    const int tid = threadIdx.x;
    const int wave = tid >> 6, lane = tid & 63;
    const int wsm = (wave >> 2) & 1, wsn = wave & 3;
    const int fr = lane & 15, g = lane >> 4;
    const int srow8 = lane >> 3;
    const int scolB = ((lane & 7) * 16) ^ (srow8 << 4);  // pre-swizzled byte

    const unsigned short* pA = A + (size_t)(wave * 16 + srow8) * lda + (scolB >> 1);
    const unsigned short* pB = B + (size_t)(wave * 16 + srow8) * ldb + (scolB >> 1);

    int offA[2][4][2], offB[2][2][2];
#pragma unroll
    for (int qm = 0; qm < 2; ++qm)
#pragma unroll
        for (int mi = 0; mi < 4; ++mi)
#pragma unroll
            for (int ks = 0; ks < 2; ++ks)
                offA[qm][mi][ks] = qm * 16384 + (wsm * 64 + mi * 16 + fr) * 128 +
                                   ((ks * 64 + g * 16) ^ ((fr & 7) << 4));
#pragma unroll
    for (int qn = 0; qn < 2; ++qn)
#pragma unroll
        for (int ni = 0; ni < 2; ++ni)
#pragma unroll
            for (int ks = 0; ks < 2; ++ks)
                offB[qn][ni][ks] = 32768 + qn * 16384 + (wsn * 32 + ni * 16 + fr) * 128 +
                                   ((ks * 64 + g * 16) ^ ((fr & 7) << 4));

#pragma unroll
    for (int qm = 0; qm < 2; ++qm)
#pragma unroll
        for (int qn = 0; qn < 2; ++qn)
#pragma unroll
            for (int mi = 0; mi < 4; ++mi)
#pragma unroll
                for (int ni = 0; ni < 2; ++ni)
                    acc[qm][qn][mi][ni] = (f32x4_t){0.f, 0.f, 0.f, 0.f};

    const int NT = K >> 6;

    // prologue: stage tile 0 into buf0 in queue order A0, B0, B1, A1
    {
        char* wb = smem;
        const size_t kof = 0;
        STA(0, 0); STA(0, 1);
        STB(0, 0); STB(0, 1);
        STB(1, 0); STB(1, 1);
        STA(1, 0); STA(1, 1);
    }

    for (int t = 0; t < NT - 1; ++t) {
        const char* rb = smem + (size_t)(t & 1) * 65536;
        char* wb = smem + (size_t)((t & 1) ^ 1) * 65536;
        tile_step<false>(rb, wb, (size_t)(t + 1) * 64, pA, pB, lda, ldb,
                         wave, offA, offB, acc);
    }
    {   // tail tile NT-1: no staging, draining waits
        const char* rb = smem + (size_t)((NT - 1) & 1) * 65536;
        tile_step<true>(rb, smem, 0, pA, pB, lda, ldb, wave, offA, offB, acc);
    }
}

// Epilogue: acc[qm][qn][mi][ni][j] ->
//   row = tm + qm*128 + wsm*64 + mi*16 + (lane>>4)*4 + j
//   col = tn + qn*128 + wsn*32 + ni*16 + (lane&15)
#define EPILOGUE_IDX                                            \
    const int lane = threadIdx.x & 63, wave = threadIdx.x >> 6; \
    const int e_r0 = ((wave >> 2) & 1) * 64 + (lane >> 4) * 4;  \
    const int e_c0 = (wave & 3) * 32 + (lane & 15);

#define EPILOGUE_LOOP(...)                                      \
    _Pragma("unroll") for (int qm = 0; qm < 2; ++qm)            \
    _Pragma("unroll") for (int qn = 0; qn < 2; ++qn)            \
    _Pragma("unroll") for (int mi = 0; mi < 4; ++mi)            \
    _Pragma("unroll") for (int ni = 0; ni < 2; ++ni)            \
    _Pragma("unroll") for (int j = 0; j < 4; ++j) { __VA_ARGS__ }

// Interleaved q/k layout: per batch z (8 total), base elem z*4194304:
//   q_z[2048][1024] at +0, k_z[2048][1024] at +2097152.
// Softmax output P_z[2048][2048] bf16 later overlays exactly this region.

// ---------------------------------------------------------------------------
// QKV GEMM, Q/K half: M=16384 tokens, N=2048 (w_qkv rows 0..2047), K=1024
// ---------------------------------------------------------------------------
__global__ __launch_bounds__(512, 2) void k_gemm_qkv_qk(
    const unsigned short* __restrict__ x, const unsigned short* __restrict__ w,
    unsigned short* __restrict__ qk) {
    __shared__ __align__(16) char smem[131072];
    const size_t tm = (size_t)blockIdx.x * 256, tn = (size_t)blockIdx.y * 256;
    f32x4_t acc[2][2][4][2];
    gemm_mainloop(x + tm * 1024, 1024, w + tn * 1024, 1024, 1024, smem, acc);
    EPILOGUE_IDX
    EPILOGUE_LOOP(
        size_t m = tm + qm * 128 + e_r0 + mi * 16 + j;
        size_t z = m >> 11;
        size_t nloc = m & 2047;
        int n = (int)tn + qn * 128 + e_c0 + ni * 16;
        unsigned short v = f2b(acc[qm][qn][mi][ni][j]);
        size_t base = z * 4194304 + nloc * 1024;
        if (n < 1024) qk[base + n] = v;
        else          qk[base + 2097152 + (n - 1024)] = v;
    )
}

// ---------------------------------------------------------------------------
// QKV GEMM, V^T half (operands swapped): M=1024 (v-weight rows), N=16384
// tokens, K=1024.  vt[c][token] = v[token][c], coalesced stores.
// ---------------------------------------------------------------------------
__global__ __launch_bounds__(512, 2) void k_gemm_vt(
    const unsigned short* __restrict__ wv, const unsigned short* __restrict__ x,
    unsigned short* __restrict__ vt) {
    __shared__ __align__(16) char smem[131072];
    const size_t tm = (size_t)blockIdx.x * 256, tn = (size_t)blockIdx.y * 256;
    f32x4_t acc[2][2][4][2];
    gemm_mainloop(wv + tm * 1024, 1024, x + tn * 1024, 1024, 1024, smem, acc);
    EPILOGUE_IDX
    EPILOGUE_LOOP(
        size_t m = tm + qm * 128 + e_r0 + mi * 16 + j;   // c
        size_t n = tn + qn * 128 + e_c0 + ni * 16;       // token
        vt[m * 16384 + n] = f2b(acc[qm][qn][mi][ni][j]);
    )
}

// ---------------------------------------------------------------------------
// Scores: batch z = z0 + blockIdx.z; S[zlocal][nq][mk] = bf16((q·k)/32)
// ---------------------------------------------------------------------------
__global__ __launch_bounds__(512, 2) void k_gemm_scores(
    const unsigned short* __restrict__ qk, unsigned short* __restrict__ S, int z0) {
    __shared__ __align__(16) char smem[131072];
    const size_t z = z0 + blockIdx.z;
    const size_t tm = (size_t)blockIdx.x * 256, tn = (size_t)blockIdx.y * 256;
    const unsigned short* qz = qk + z * 4194304;
    const unsigned short* kz = qz + 2097152;
    f32x4_t acc[2][2][4][2];
    gemm_mainloop(qz + tm * 1024, 1024, kz + tn * 1024, 1024, 1024, smem, acc);
    EPILOGUE_IDX
    unsigned short* Sz = S + (size_t)blockIdx.z * 4194304;
    EPILOGUE_LOOP(
        size_t m = tm + qm * 128 + e_r0 + mi * 16 + j;
        size_t n = tn + qn * 128 + e_c0 + ni * 16;
        Sz[m * 2048 + n] = f2b(acc[qm][qn][mi][ni][j] * 0.03125f);
    )
}

// ---------------------------------------------------------------------------
// Row softmax: NZ*2048 rows x 2048, bf16 in -> bf16 out (P overlays q/k)
// One 16B vector (8 bf16) per thread.
// ---------------------------------------------------------------------------
__global__ __launch_bounds__(256) void k_softmax(const unsigned short* __restrict__ S,
                                                 unsigned short* __restrict__ qk,
                                                 int z0) {
    const size_t r = blockIdx.x;                 // row within chunk
    const int t = threadIdx.x, wv = t >> 6, ln = t & 63;
    const uint4 u = reinterpret_cast<const uint4*>(S + r * 2048)[t];
    float vals[8];
    vals[0] = b2f((unsigned short)(u.x & 0xffff)); vals[1] = b2f((unsigned short)(u.x >> 16));
    vals[2] = b2f((unsigned short)(u.y & 0xffff)); vals[3] = b2f((unsigned short)(u.y >> 16));
    vals[4] = b2f((unsigned short)(u.z & 0xffff)); vals[5] = b2f((unsigned short)(u.z >> 16));
    vals[6] = b2f((unsigned short)(u.w & 0xffff)); vals[7] = b2f((unsigned short)(u.w >> 16));

    float mx = vals[0];
#pragma unroll
    for (int i = 1; i < 8; ++i) mx = fmaxf(mx, vals[i]);
#pragma unroll
    for (int i = 32; i > 0; i >>= 1) mx = fmaxf(mx, __shfl_xor(mx, i, 64));
    __shared__ float red[8];
    if (ln == 0) red[wv] = mx;
    __syncthreads();
    mx = fmaxf(fmaxf(red[0], red[1]), fmaxf(red[2], red[3]));

    float ex[8], s = 0.f;
#pragma unroll
    for (int i = 0; i < 8; ++i) { ex[i] = __expf(vals[i] - mx); s += ex[i]; }
#pragma unroll
    for (int i = 32; i > 0; i >>= 1) s += __shfl_xor(s, i, 64);
    if (ln == 0) red[4 + wv] = s;
    __syncthreads();
    s = (red[4] + red[5]) + (red[6] + red[7]);
    float inv = 1.0f / s;

    uint4 o;
    o.x = (unsigned)f2b(ex[0] * inv) | ((unsigned)f2b(ex[1] * inv) << 16);
    o.y = (unsigned)f2b(ex[2] * inv) | ((unsigned)f2b(ex[3] * inv) << 16);
    o.z = (unsigned)f2b(ex[4] * inv) | ((unsigned)f2b(ex[5] * inv) << 16);
    o.w = (unsigned)f2b(ex[6] * inv) | ((unsigned)f2b(ex[7] * inv) << 16);

    const size_t zg = z0 + (r >> 11), nloc = r & 2047;
    reinterpret_cast<uint4*>(qk + zg * 4194304 + nloc * 2048)[t] = o;
}

// ---------------------------------------------------------------------------
// PV as O^T: batch z = z0+blockIdx.z, O^T[c][n] = sum_m vt[c][m] * P[n][m]
// M=1024 (c), N=2048 (n), K=2048.  Stores apply the swapaxes-reshape
// scramble o2[2c + (n>>10)][n&1023] = o[n][c] -> coalesced in n.
// ---------------------------------------------------------------------------
__global__ __launch_bounds__(512, 2) void k_gemm_pv(
    const unsigned short* __restrict__ vt, const unsigned short* __restrict__ qk,
    unsigned short* __restrict__ ob, int z0) {
    __shared__ __align__(16) char smem[131072];
    const size_t z = z0 + blockIdx.z;
    const size_t tm = (size_t)blockIdx.x * 256, tn = (size_t)blockIdx.y * 256;
    const unsigned short* P = qk + z * 4194304;
    f32x4_t acc[2][2][4][2];
    gemm_mainloop(vt + tm * 16384 + z * 2048, 16384,
                  P + tn * 2048, 2048, 2048, smem, acc);
    EPILOGUE_IDX
    unsigned short* oz = ob + z * 2097152;
    EPILOGUE_LOOP(
        size_t m = tm + qm * 128 + e_r0 + mi * 16 + j;   // c
        size_t n = tn + qn * 128 + e_c0 + ni * 16;       // token n within batch
        oz[(2 * m + (n >> 10)) * 1024 + (n & 1023)] = f2b(acc[qm][qn][mi][ni][j]);
    )
}

// ---------------------------------------------------------------------------
// Proj: out[m][d] = sum_j o2[m][j] * w_proj[d][j] + b_proj[d], fp32 out
// M=16384, N=1024, K=1024
// ---------------------------------------------------------------------------
__global__ __launch_bounds__(512, 2) void k_gemm_proj(
    const unsigned short* __restrict__ o2, const unsigned short* __restrict__ w,
    const float* __restrict__ bias, float* __restrict__ out) {
    __shared__ __align__(16) char smem[131072];
    const size_t tm = (size_t)blockIdx.x * 256, tn = (size_t)blockIdx.y * 256;
    f32x4_t acc[2][2][4][2];
    gemm_mainloop(o2 + tm * 1024, 1024, w + tn * 1024, 1024, 1024, smem, acc);
    EPILOGUE_IDX
    EPILOGUE_LOOP(
        size_t m = tm + qm * 128 + e_r0 + mi * 16 + j;
        size_t n = tn + qn * 128 + e_c0 + ni * 16;
        out[m * 1024 + n] = acc[qm][qn][mi][ni][j] + bias[n];
    )
}

// ---------------------------------------------------------------------------
extern "C" void kernel_launch(void* const* d_in, const int* in_sizes, int n_in,
                              void* d_out, int out_size, void* d_ws, size_t ws_size,
                              hipStream_t stream) {
    const float* x     = (const float*)d_in[0];
    const float* wqkv  = (const float*)d_in[1];
    const float* wproj = (const float*)d_in[2];
    const float* bproj = (const float*)d_in[3];
    float* out = (float*)d_out;
    char* ws = (char*)d_ws;

    // workspace layout (bytes):
    const size_t off_xb    = 0;             // 33,554,432 x bf16 (obuf overlays)
    const size_t off_wqkv  = 33554432;      //  6,291,456
    const size_t off_wproj = 39845888;      //  2,097,152
    const size_t off_qk    = 41943040;      // 67,108,864 interleaved q/k (P overlays)
    const size_t off_vt    = 109051904;     // 33,554,432
    const size_t off_S     = 142606336;     // NZ * 8,388,608 bf16 logits chunk
    // adaptive chunk: largest NZ in {8,4,2,1} that fits
    int NZ = 0;
    for (int c = 8; c >= 1; c >>= 1)
        if (off_S + (size_t)c * 8388608 <= ws_size) { NZ = c; break; }
    if (NZ == 0) return;  // fail loudly via absmax check

    unsigned short* xb     = (unsigned short*)(ws + off_xb);
    unsigned short* wqkvb  = (unsigned short*)(ws + off_wqkv);
    unsigned short* wprojb = (unsigned short*)(ws + off_wproj);
    unsigned short* qkb    = (unsigned short*)(ws + off_qk);
    unsigned short* vtb    = (unsigned short*)(ws + off_vt);
    unsigned short* Sb     = (unsigned short*)(ws + off_S);
    unsigned short* obuf   = (unsigned short*)(ws + off_xb);  // overlay

    k_f2b<<<16384, 256, 0, stream>>>(x, xb, 4194304);
    k_f2b<<<3072, 256, 0, stream>>>(wqkv, wqkvb, 786432);
    k_f2b<<<1024, 256, 0, stream>>>(wproj, wprojb, 262144);

    k_gemm_qkv_qk<<<dim3(64, 8), 512, 0, stream>>>(xb, wqkvb, qkb);
    k_gemm_vt<<<dim3(4, 64), 512, 0, stream>>>(wqkvb + (size_t)2048 * 1024, xb, vtb);

    for (int z0 = 0; z0 < 8; z0 += NZ) {
        k_gemm_scores<<<dim3(8, 8, NZ), 512, 0, stream>>>(qkb, Sb, z0);
        k_softmax<<<NZ * 2048, 256, 0, stream>>>(Sb, qkb, z0);
        k_gemm_pv<<<dim3(4, 8, NZ), 512, 0, stream>>>(vtb, qkb, obuf, z0);
    }
    k_gemm_proj<<<dim3(64, 4), 512, 0, stream>>>(obuf, wprojb, bproj, out);
}